// Round 1
// baseline (128.847 us; speedup 1.0000x reference)
//
#include <hip/hip_runtime.h>

// Bilinear table interpolation, TF _interpolate_bilinear semantics.
//
// R6: NO-WORKSPACE experiment. Evidence from R5 rocprof: top-5 dispatches are
// five 256MiB fillBufferAligned (~44us each) = harness d_ws re-poison; every
// dispatch of ours is <43.6us, so build+interp <= ~48us realistic, yet
// dur_us=114 -> the timed region contains ws-poison fill(s). Hypothesis: the
// poison is conditional on ws use. This version gathers straight from the
// fp32 grid (4MiB = exactly per-XCD L2), 2x8B gathers/pt sharing ONE 64-bit
// address (+-2048B immediate offsets), 8 pts/thread, all 16 gathers batched.
// nt loads/stores keep the streams from evicting the grid out of L2.
// Bonus: exact fp32 (absmax ~1e-6 vs 0.03125), single launch.

#define GRID_H 1024
#define GRID_W 1024

typedef float floatx4 __attribute__((ext_vector_type(4)));
typedef float floatx2 __attribute__((ext_vector_type(2)));

__global__ __launch_bounds__(256) void interpRaw8_kernel(
    const float* __restrict__ in,        // N*2 floats (x, v)
    const float* __restrict__ grid,      // H*W fp32
    const float* __restrict__ bounds,    // [x_lo,x_hi,v_lo,v_hi]
    float* __restrict__ out,             // N floats
    int n_pts)
{
    const int H = GRID_H, W = GRID_W;
    const float x_lo = bounds[0];
    const float x_hi = bounds[1];
    const float v_lo = bounds[2];
    const float v_hi = bounds[3];
    const float sy = (float)(H - 1) / (x_hi - x_lo);
    const float sx = (float)(W - 1) / (v_hi - v_lo);

    const int t = blockIdx.x * blockDim.x + threadIdx.x;
    const int base = t * 8;
    if (base >= n_pts) return;

    float xs[8], vs[8], res[8];

    if (base + 7 < n_pts) {
        const floatx4* in4 = (const floatx4*)in;
#pragma unroll
        for (int q = 0; q < 4; ++q) {
            floatx4 p = __builtin_nontemporal_load(&in4[4 * t + q]);
            xs[2 * q + 0] = p.x; vs[2 * q + 0] = p.y;
            xs[2 * q + 1] = p.z; vs[2 * q + 1] = p.w;
        }
    } else {
#pragma unroll
        for (int k = 0; k < 8; ++k) {
            int p = base + k < n_pts ? base + k : n_pts - 1;
            xs[k] = in[2 * p + 0];
            vs[k] = in[2 * p + 1];
        }
    }

    // Address math. Bias the per-point base by +512 floats (+2048B) so both
    // row loads are immediate offsets (-2048 / +2048, within 13-bit signed)
    // off a SINGLE 64-bit VGPR address pair: row stride 4096B itself is not
    // encodable as an immediate.
    float ays[8], axs[8];
    const float* gp[8];
#pragma unroll
    for (int k = 0; k < 8; ++k) {
        float qy = (xs[k] - x_lo) * sy;
        float qx = (vs[k] - v_lo) * sx;
        float fy = fminf(fmaxf(floorf(qy), 0.0f), (float)(H - 2));
        float fx = fminf(fmaxf(floorf(qx), 0.0f), (float)(W - 2));
        ays[k] = fminf(fmaxf(qy - fy, 0.0f), 1.0f);
        axs[k] = fminf(fmaxf(qx - fx, 0.0f), 1.0f);
        gp[k] = grid + (((int)fy << 10) + (int)fx + 512);
    }

    // Batch all 16 gathers (8B each: columns x0,x0+1 of rows y0 and y0+1)
    // before any use -> 16 loads in flight per thread.
    floatx2 t2[8], b2[8];
#pragma unroll
    for (int k = 0; k < 8; ++k) t2[k] = *(const floatx2*)(gp[k] - 512);
#pragma unroll
    for (int k = 0; k < 8; ++k) b2[k] = *(const floatx2*)(gp[k] + 512);

#pragma unroll
    for (int k = 0; k < 8; ++k) {
        float top = t2[k].x + (t2[k].y - t2[k].x) * axs[k];
        float bot = b2[k].x + (b2[k].y - b2[k].x) * axs[k];
        res[k] = top + (bot - top) * ays[k];
    }

    if (base + 7 < n_pts) {
        floatx4* out4 = (floatx4*)out;
#pragma unroll
        for (int q = 0; q < 2; ++q) {
            floatx4 o;
            o.x = res[4 * q + 0]; o.y = res[4 * q + 1];
            o.z = res[4 * q + 2]; o.w = res[4 * q + 3];
            __builtin_nontemporal_store(o, &out4[2 * t + q]);
        }
    } else {
#pragma unroll
        for (int k = 0; k < 8; ++k)
            if (base + k < n_pts) out[base + k] = res[k];
    }
}

extern "C" void kernel_launch(void* const* d_in, const int* in_sizes, int n_in,
                              void* d_out, int out_size, void* d_ws, size_t ws_size,
                              hipStream_t stream) {
    const float* in     = (const float*)d_in[0];   // (N, 2) fp32
    const float* grid   = (const float*)d_in[1];   // (H, W) fp32
    const float* bounds = (const float*)d_in[2];   // (2, 2) fp32
    float* out = (float*)d_out;                    // N fp32

    const int n_pts = in_sizes[0] / 2;
    const int n_threads = (n_pts + 7) / 8;
    // d_ws deliberately UNUSED this round (poison-tax A/B).
    (void)d_ws; (void)ws_size;
    interpRaw8_kernel<<<(n_threads + 255) / 256, 256, 0, stream>>>(
        in, grid, bounds, out, n_pts);
}

// Round 2
// 122.385 us; speedup vs baseline: 1.0528x; 1.0528x over previous
//
#include <hip/hip_runtime.h>

// Bilinear table interpolation, TF _interpolate_bilinear semantics.
//
// R7: revert to the pair-table structure (R5, proven 114.3 vs 128.8 for raw
// gather) + ONE change: 16 points/thread (was 8). R6 established:
//   - harness tax is a fixed ~73.6us (unconditional 256MiB ws poison fill),
//     identical whether or not d_ws is used -> only kernel time matters.
//   - gather rate ~0.25 req/cy/CU, VALUBusy 5%, HBM 20% -> concurrency/
//     latency bound, not BW bound.
// Doubling batched gathers per wave (8 -> 16 vmem items in flight) tests the
// per-wave-outstanding-limit hypothesis. qidx kept as 32-bit voffsets vs a
// uniform SGPR base to stay ~110 VGPR (no spill).
//
// Table: P[y][x] = bf16(grid[y][x]) | bf16(grid[y+1][x])<<16, (H-1)*W entries,
// 4.19MB (fits per-XCD L2). One 8B gather/point returns all 4 corners.

#define GRID_H 1024
#define GRID_W 1024
#define PTS 16

typedef float floatx4 __attribute__((ext_vector_type(4)));
typedef float floatx2 __attribute__((ext_vector_type(2)));
typedef unsigned int uintx2 __attribute__((ext_vector_type(2)));
typedef unsigned int uintx4 __attribute__((ext_vector_type(4)));

__device__ __forceinline__ unsigned int f32_to_bf16_rne(float f) {
    unsigned int u = __builtin_bit_cast(unsigned int, f);
    u += 0x7fffu + ((u >> 16) & 1u);   // round-to-nearest-even
    return u >> 16;
}

// ---------- prep: build packed row-pair table ----------
__global__ __launch_bounds__(256) void buildPair_kernel(
    const float* __restrict__ grid,      // H*W
    unsigned int* __restrict__ pair,     // (H-1)*W entries
    int n_groups)                        // (H-1)*W/4
{
    int g = blockIdx.x * blockDim.x + threadIdx.x;
    if (g >= n_groups) return;
    int idx = g * 4;
    int y = idx >> 10;                   // / GRID_W
    int x = idx & (GRID_W - 1);          // multiple of 4
    const floatx4* r0 = (const floatx4*)(grid + (y << 10) + x);
    const floatx4* r1 = (const floatx4*)(grid + ((y + 1) << 10) + x);
    floatx4 t = *r0;
    floatx4 b = *r1;
    uintx4 o;
    o.x = f32_to_bf16_rne(t.x) | (f32_to_bf16_rne(b.x) << 16);
    o.y = f32_to_bf16_rne(t.y) | (f32_to_bf16_rne(b.y) << 16);
    o.z = f32_to_bf16_rne(t.z) | (f32_to_bf16_rne(b.z) << 16);
    o.w = f32_to_bf16_rne(t.w) | (f32_to_bf16_rne(b.w) << 16);
    *(uintx4*)(pair + idx) = o;
}

// ---------- main: 16 points/thread, ONE 8B gather per point ----------
__global__ __launch_bounds__(256) void interpPair16_kernel(
    const float* __restrict__ in,            // N*2 floats (x, v)
    const unsigned int* __restrict__ pair,   // packed table
    const float* __restrict__ bounds,        // [x_lo,x_hi,v_lo,v_hi]
    float* __restrict__ out,                 // N floats
    int n_pts)
{
    const int H = GRID_H, W = GRID_W;
    const float x_lo = bounds[0];
    const float x_hi = bounds[1];
    const float v_lo = bounds[2];
    const float v_hi = bounds[3];
    const float sy = (float)(H - 1) / (x_hi - x_lo);
    const float sx = (float)(W - 1) / (v_hi - v_lo);

    const int t = blockIdx.x * blockDim.x + threadIdx.x;
    const int base = t * PTS;
    if (base >= n_pts) return;

    float xs[PTS], vs[PTS], res[PTS];

    if (base + PTS - 1 < n_pts) {
        const floatx4* in4 = (const floatx4*)in;
#pragma unroll
        for (int q = 0; q < PTS / 2; ++q) {        // 8 x 16B nt loads
            floatx4 p = __builtin_nontemporal_load(&in4[(PTS / 2) * t + q]);
            xs[2 * q + 0] = p.x; vs[2 * q + 0] = p.y;
            xs[2 * q + 1] = p.z; vs[2 * q + 1] = p.w;
        }
    } else {
#pragma unroll
        for (int k = 0; k < PTS; ++k) {
            int p = base + k < n_pts ? base + k : n_pts - 1;
            xs[k] = in[2 * p + 0];
            vs[k] = in[2 * p + 1];
        }
    }

    float ays[PTS], axs[PTS];
    int qidx[PTS];                       // 32-bit offsets -> saddr+voffset form
#pragma unroll
    for (int k = 0; k < PTS; ++k) {
        float qy = (xs[k] - x_lo) * sy;
        float qx = (vs[k] - v_lo) * sx;
        float fy = fminf(fmaxf(floorf(qy), 0.0f), (float)(H - 2));
        float fx = fminf(fmaxf(floorf(qx), 0.0f), (float)(W - 2));
        ays[k] = fminf(fmaxf(qy - fy, 0.0f), 1.0f);
        axs[k] = fminf(fmaxf(qx - fx, 0.0f), 1.0f);
        qidx[k] = ((int)fy << 10) + (int)fx;   // y0*W + x0
    }

    // Batch 16 gathers (one 8B load each -> entries x0 and x0+1) before use:
    // 16 vmem items in flight per wave.
    uintx2 c[PTS];
#pragma unroll
    for (int k = 0; k < PTS; ++k)
        c[k] = *(const uintx2*)(pair + qidx[k]);

#pragma unroll
    for (int k = 0; k < PTS; ++k) {
        float tl = __builtin_bit_cast(float, c[k].x << 16);
        float bl = __builtin_bit_cast(float, c[k].x & 0xffff0000u);
        float tr = __builtin_bit_cast(float, c[k].y << 16);
        float br = __builtin_bit_cast(float, c[k].y & 0xffff0000u);
        float top = tl + (tr - tl) * axs[k];
        float bot = bl + (br - bl) * axs[k];
        res[k] = top + (bot - top) * ays[k];
    }

    if (base + PTS - 1 < n_pts) {
        floatx4* out4 = (floatx4*)out;
#pragma unroll
        for (int q = 0; q < PTS / 4; ++q) {        // 4 x 16B nt stores
            floatx4 o;
            o.x = res[4 * q + 0]; o.y = res[4 * q + 1];
            o.z = res[4 * q + 2]; o.w = res[4 * q + 3];
            __builtin_nontemporal_store(o, &out4[(PTS / 4) * t + q]);
        }
    } else {
#pragma unroll
        for (int k = 0; k < PTS; ++k)
            if (base + k < n_pts) out[base + k] = res[k];
    }
}

// ---------- fallback if d_ws is too small ----------
__global__ __launch_bounds__(256) void interpRaw_kernel(
    const float* __restrict__ in, const float* __restrict__ grid,
    const float* __restrict__ bounds, float* __restrict__ out, int n_pts)
{
    const int H = GRID_H, W = GRID_W;
    const float x_lo = bounds[0], x_hi = bounds[1];
    const float v_lo = bounds[2], v_hi = bounds[3];
    const float sy = (float)(H - 1) / (x_hi - x_lo);
    const float sx = (float)(W - 1) / (v_hi - v_lo);
    const int t = blockIdx.x * blockDim.x + threadIdx.x;
    const int base = t * 4;
    if (base >= n_pts) return;
    float xs[4], vs[4], res[4];
#pragma unroll
    for (int k = 0; k < 4; ++k) {
        int p = base + k < n_pts ? base + k : n_pts - 1;
        xs[k] = in[2 * p + 0];
        vs[k] = in[2 * p + 1];
    }
    float ays[4], axs[4];
    const floatx2 *gt[4], *gb[4];
#pragma unroll
    for (int k = 0; k < 4; ++k) {
        float qy = (xs[k] - x_lo) * sy;
        float qx = (vs[k] - v_lo) * sx;
        float fy = fminf(fmaxf(floorf(qy), 0.0f), (float)(H - 2));
        float fx = fminf(fmaxf(floorf(qx), 0.0f), (float)(W - 2));
        ays[k] = fminf(fmaxf(qy - fy, 0.0f), 1.0f);
        axs[k] = fminf(fmaxf(qx - fx, 0.0f), 1.0f);
        const float* g = grid + ((int)fy << 10) + (int)fx;
        gt[k] = (const floatx2*)g;
        gb[k] = (const floatx2*)(g + W);
    }
    floatx2 t2[4], b2[4];
#pragma unroll
    for (int k = 0; k < 4; ++k) { t2[k] = *gt[k]; b2[k] = *gb[k]; }
#pragma unroll
    for (int k = 0; k < 4; ++k) {
        float top = t2[k].x + (t2[k].y - t2[k].x) * axs[k];
        float bot = b2[k].x + (b2[k].y - b2[k].x) * axs[k];
        res[k] = top + (bot - top) * ays[k];
    }
#pragma unroll
    for (int k = 0; k < 4; ++k)
        if (base + k < n_pts) out[base + k] = res[k];
}

extern "C" void kernel_launch(void* const* d_in, const int* in_sizes, int n_in,
                              void* d_out, int out_size, void* d_ws, size_t ws_size,
                              hipStream_t stream) {
    const float* in     = (const float*)d_in[0];   // (N, 2) fp32
    const float* grid   = (const float*)d_in[1];   // (H, W) fp32
    const float* bounds = (const float*)d_in[2];   // (2, 2) fp32
    float* out = (float*)d_out;                    // N fp32

    const int n_pts = in_sizes[0] / 2;
    const int n_entries = (GRID_H - 1) * GRID_W;           // 1023*1024
    const size_t pair_bytes = (size_t)n_entries * 4;       // 4.19 MB

    if (ws_size >= pair_bytes) {
        unsigned int* pair = (unsigned int*)d_ws;
        const int n_groups = n_entries / 4;                // W % 4 == 0
        buildPair_kernel<<<(n_groups + 255) / 256, 256, 0, stream>>>(grid, pair, n_groups);
        const int n_threads = (n_pts + PTS - 1) / PTS;
        interpPair16_kernel<<<(n_threads + 255) / 256, 256, 0, stream>>>(
            in, pair, bounds, out, n_pts);
    } else {
        const int n_threads = (n_pts + 3) / 4;
        interpRaw_kernel<<<(n_threads + 255) / 256, 256, 0, stream>>>(
            in, grid, bounds, out, n_pts);
    }
}

// Round 3
// 110.869 us; speedup vs baseline: 1.1622x; 1.1039x over previous
//
#include <hip/hip_runtime.h>

// Bilinear table interpolation, TF _interpolate_bilinear semantics.
//
// R8: pair table (proven best) + PTS=4 (was 8 in R5, 16 in R7).
// Evidence ladder:
//   R5 pair/PTS8, 2048 blk (exact wave fill): interp ~36.7us, total 114.3
//   R7 pair/PTS16, 1024 blk (50% cap):       interp  47.5us, total 122.4
//     -> equal in-flight instrs/CU (256) but avg occupancy 27% -> residency,
//        not batch depth, is the lever for gather throughput.
//   R6 raw fp32 (2 gathers/pt):              interp  55.2us  -> 1 gather/pt wins.
// PTS=4 -> 4096 blocks = 2x oversubscription -> scheduler refills as blocks
// retire -> higher average occupancy through the drain. Batch 4 x 32 waves/CU
// = 128 in-flight gather instrs/CU, still >> inferred per-CU miss depth (~64).
//
// Table: P[y][x] = bf16(grid[y][x]) | bf16(grid[y+1][x])<<16, (H-1)*W entries,
// 4.19MB. ONE 8B gather/point returns all 4 corners (tl,bl,tr,br).
// Harness tax (unconditional 256MiB ws poison, ~73.6us) is fixed; only kernel
// time is in play.

#define GRID_H 1024
#define GRID_W 1024
#define PTS 4

typedef float floatx4 __attribute__((ext_vector_type(4)));
typedef float floatx2 __attribute__((ext_vector_type(2)));
typedef unsigned int uintx2 __attribute__((ext_vector_type(2)));
typedef unsigned int uintx4 __attribute__((ext_vector_type(4)));

__device__ __forceinline__ unsigned int f32_to_bf16_rne(float f) {
    unsigned int u = __builtin_bit_cast(unsigned int, f);
    u += 0x7fffu + ((u >> 16) & 1u);   // round-to-nearest-even
    return u >> 16;
}

// ---------- prep: build packed row-pair table ----------
__global__ __launch_bounds__(256) void buildPair_kernel(
    const float* __restrict__ grid,      // H*W
    unsigned int* __restrict__ pair,     // (H-1)*W entries
    int n_groups)                        // (H-1)*W/4
{
    int g = blockIdx.x * blockDim.x + threadIdx.x;
    if (g >= n_groups) return;
    int idx = g * 4;
    int y = idx >> 10;                   // / GRID_W
    int x = idx & (GRID_W - 1);          // multiple of 4
    const floatx4* r0 = (const floatx4*)(grid + (y << 10) + x);
    const floatx4* r1 = (const floatx4*)(grid + ((y + 1) << 10) + x);
    floatx4 t = *r0;
    floatx4 b = *r1;
    uintx4 o;
    o.x = f32_to_bf16_rne(t.x) | (f32_to_bf16_rne(b.x) << 16);
    o.y = f32_to_bf16_rne(t.y) | (f32_to_bf16_rne(b.y) << 16);
    o.z = f32_to_bf16_rne(t.z) | (f32_to_bf16_rne(b.z) << 16);
    o.w = f32_to_bf16_rne(t.w) | (f32_to_bf16_rne(b.w) << 16);
    *(uintx4*)(pair + idx) = o;
}

// ---------- main: 4 points/thread, ONE 8B gather per point ----------
__global__ __launch_bounds__(256) void interpPair4_kernel(
    const float* __restrict__ in,            // N*2 floats (x, v)
    const unsigned int* __restrict__ pair,   // packed table
    const float* __restrict__ bounds,        // [x_lo,x_hi,v_lo,v_hi]
    float* __restrict__ out,                 // N floats
    int n_pts)
{
    const int H = GRID_H, W = GRID_W;
    const float x_lo = bounds[0];
    const float x_hi = bounds[1];
    const float v_lo = bounds[2];
    const float v_hi = bounds[3];
    const float sy = (float)(H - 1) / (x_hi - x_lo);
    const float sx = (float)(W - 1) / (v_hi - v_lo);

    const int t = blockIdx.x * blockDim.x + threadIdx.x;
    const int base = t * PTS;
    if (base >= n_pts) return;

    float xs[PTS], vs[PTS], res[PTS];

    if (base + PTS - 1 < n_pts) {
        const floatx4* in4 = (const floatx4*)in;
#pragma unroll
        for (int q = 0; q < PTS / 2; ++q) {        // 2 x 16B nt loads
            floatx4 p = __builtin_nontemporal_load(&in4[(PTS / 2) * t + q]);
            xs[2 * q + 0] = p.x; vs[2 * q + 0] = p.y;
            xs[2 * q + 1] = p.z; vs[2 * q + 1] = p.w;
        }
    } else {
#pragma unroll
        for (int k = 0; k < PTS; ++k) {
            int p = base + k < n_pts ? base + k : n_pts - 1;
            xs[k] = in[2 * p + 0];
            vs[k] = in[2 * p + 1];
        }
    }

    float ays[PTS], axs[PTS];
    int qidx[PTS];
#pragma unroll
    for (int k = 0; k < PTS; ++k) {
        float qy = (xs[k] - x_lo) * sy;
        float qx = (vs[k] - v_lo) * sx;
        float fy = fminf(fmaxf(floorf(qy), 0.0f), (float)(H - 2));
        float fx = fminf(fmaxf(floorf(qx), 0.0f), (float)(W - 2));
        ays[k] = fminf(fmaxf(qy - fy, 0.0f), 1.0f);
        axs[k] = fminf(fmaxf(qx - fx, 0.0f), 1.0f);
        qidx[k] = ((int)fy << 10) + (int)fx;   // y0*W + x0
    }

    // Batch the 4 gathers (one 8B load each -> entries x0 and x0+1) before use.
    uintx2 c[PTS];
#pragma unroll
    for (int k = 0; k < PTS; ++k)
        c[k] = *(const uintx2*)(pair + qidx[k]);

#pragma unroll
    for (int k = 0; k < PTS; ++k) {
        float tl = __builtin_bit_cast(float, c[k].x << 16);
        float bl = __builtin_bit_cast(float, c[k].x & 0xffff0000u);
        float tr = __builtin_bit_cast(float, c[k].y << 16);
        float br = __builtin_bit_cast(float, c[k].y & 0xffff0000u);
        float top = tl + (tr - tl) * axs[k];
        float bot = bl + (br - bl) * axs[k];
        res[k] = top + (bot - top) * ays[k];
    }

    if (base + PTS - 1 < n_pts) {
        floatx4* out4 = (floatx4*)out;
        floatx4 o;
        o.x = res[0]; o.y = res[1]; o.z = res[2]; o.w = res[3];
        __builtin_nontemporal_store(o, &out4[t]);  // 1 x 16B nt store
    } else {
#pragma unroll
        for (int k = 0; k < PTS; ++k)
            if (base + k < n_pts) out[base + k] = res[k];
    }
}

// ---------- fallback if d_ws is too small ----------
__global__ __launch_bounds__(256) void interpRaw_kernel(
    const float* __restrict__ in, const float* __restrict__ grid,
    const float* __restrict__ bounds, float* __restrict__ out, int n_pts)
{
    const int H = GRID_H, W = GRID_W;
    const float x_lo = bounds[0], x_hi = bounds[1];
    const float v_lo = bounds[2], v_hi = bounds[3];
    const float sy = (float)(H - 1) / (x_hi - x_lo);
    const float sx = (float)(W - 1) / (v_hi - v_lo);
    const int t = blockIdx.x * blockDim.x + threadIdx.x;
    const int base = t * 4;
    if (base >= n_pts) return;
    float xs[4], vs[4], res[4];
#pragma unroll
    for (int k = 0; k < 4; ++k) {
        int p = base + k < n_pts ? base + k : n_pts - 1;
        xs[k] = in[2 * p + 0];
        vs[k] = in[2 * p + 1];
    }
    float ays[4], axs[4];
    const floatx2 *gt[4], *gb[4];
#pragma unroll
    for (int k = 0; k < 4; ++k) {
        float qy = (xs[k] - x_lo) * sy;
        float qx = (vs[k] - v_lo) * sx;
        float fy = fminf(fmaxf(floorf(qy), 0.0f), (float)(H - 2));
        float fx = fminf(fmaxf(floorf(qx), 0.0f), (float)(W - 2));
        ays[k] = fminf(fmaxf(qy - fy, 0.0f), 1.0f);
        axs[k] = fminf(fmaxf(qx - fx, 0.0f), 1.0f);
        const float* g = grid + ((int)fy << 10) + (int)fx;
        gt[k] = (const floatx2*)g;
        gb[k] = (const floatx2*)(g + W);
    }
    floatx2 t2[4], b2[4];
#pragma unroll
    for (int k = 0; k < 4; ++k) { t2[k] = *gt[k]; b2[k] = *gb[k]; }
#pragma unroll
    for (int k = 0; k < 4; ++k) {
        float top = t2[k].x + (t2[k].y - t2[k].x) * axs[k];
        float bot = b2[k].x + (b2[k].y - b2[k].x) * axs[k];
        res[k] = top + (bot - top) * ays[k];
    }
#pragma unroll
    for (int k = 0; k < 4; ++k)
        if (base + k < n_pts) out[base + k] = res[k];
}

extern "C" void kernel_launch(void* const* d_in, const int* in_sizes, int n_in,
                              void* d_out, int out_size, void* d_ws, size_t ws_size,
                              hipStream_t stream) {
    const float* in     = (const float*)d_in[0];   // (N, 2) fp32
    const float* grid   = (const float*)d_in[1];   // (H, W) fp32
    const float* bounds = (const float*)d_in[2];   // (2, 2) fp32
    float* out = (float*)d_out;                    // N fp32

    const int n_pts = in_sizes[0] / 2;
    const int n_entries = (GRID_H - 1) * GRID_W;           // 1023*1024
    const size_t pair_bytes = (size_t)n_entries * 4;       // 4.19 MB

    if (ws_size >= pair_bytes) {
        unsigned int* pair = (unsigned int*)d_ws;
        const int n_groups = n_entries / 4;                // W % 4 == 0
        buildPair_kernel<<<(n_groups + 255) / 256, 256, 0, stream>>>(grid, pair, n_groups);
        const int n_threads = (n_pts + PTS - 1) / PTS;
        interpPair4_kernel<<<(n_threads + 255) / 256, 256, 0, stream>>>(
            in, pair, bounds, out, n_pts);
    } else {
        const int n_threads = (n_pts + 3) / 4;
        interpRaw_kernel<<<(n_threads + 255) / 256, 256, 0, stream>>>(
            in, grid, bounds, out, n_pts);
    }
}